// Round 10
// baseline (752.016 us; speedup 1.0000x reference)
//
#include <hip/hip_runtime.h>

constexpr int N_NODES = 40000;
constexpr int N_EDGES = 640000;

constexpr float C_INV8     = 0.125f;                  // 1/sqrt(64)
constexpr float C_INV_S32  = 0.17677669529663687f;    // 1/sqrt(32)
constexpr float C_INV_S3   = 0.57735026918962576f;    // 1/sqrt(3)
constexpr float C_INV_S2   = 0.70710678118654752f;    // 1/sqrt(2)
constexpr float C_INV_S96  = 0.10206207261596575f;    // 1/sqrt(96)
constexpr float C_INV_S128 = 0.08838834764831845f;    // 1/sqrt(128)
constexpr float C_INV_NN   = 0.25f;                   // 1/sqrt(16)

typedef __attribute__((ext_vector_type(8))) short short8;
typedef __attribute__((ext_vector_type(4))) float f32x4;

__device__ __forceinline__ unsigned short f2bf(float x) {
  __bf16 b = (__bf16)x;                      // hw v_cvt (RNE)
  return __builtin_bit_cast(unsigned short, b);
}
__device__ __forceinline__ float bf2f(unsigned short h) {
  return __uint_as_float(((unsigned int)h) << 16);
}

// ---- K1: fused node linears + weight prep (tail blocks) ----
constexpr int NODE_BLOCKS = (N_NODES * 96 + 255) / 256;   // 15000
constexpr int PREP_BLOCKS = 124;

__global__ __launch_bounds__(256) void k_pre(
    const float* __restrict__ nf, const float* __restrict__ attr,
    const float* __restrict__ ws_, const float* __restrict__ wv_,
    const float* __restrict__ fc_w1, const float* __restrict__ fc_w2,
    const float* __restrict__ lin2_ws, const float* __restrict__ lin2_wv,
    float* __restrict__ h_s, float* __restrict__ h_v,
    unsigned short* __restrict__ w1t, unsigned short* __restrict__ w2t,
    unsigned short* __restrict__ wst, unsigned short* __restrict__ wvt)
{
  if (blockIdx.x < NODE_BLOCKS) {
    int t = blockIdx.x * 256 + threadIdx.x;
    if (t < N_NODES * 64) {
      int n = t >> 6, c = t & 63;
      const float* s = nf + (long)n * 160;
      float acc = 0.f;
      #pragma unroll 8
      for (int k = 0; k < 64; ++k) acc = fmaf(s[k], ws_[k * 64 + c], acc);
      h_s[t] = acc * attr[n] * C_INV8;
    } else {
      int u = t - N_NODES * 64;
      if (u >= N_NODES * 32) return;
      int n = u >> 5, d = u & 31;
      const float* v = nf + (long)n * 160 + 64;
      float a0 = 0.f, a1 = 0.f, a2 = 0.f;
      #pragma unroll 8
      for (int c = 0; c < 32; ++c) {
        float wv = wv_[c * 32 + d];
        a0 = fmaf(v[3 * c + 0], wv, a0);
        a1 = fmaf(v[3 * c + 1], wv, a1);
        a2 = fmaf(v[3 * c + 2], wv, a2);
      }
      float sc = attr[n] * C_INV_S32;
      h_v[(long)u * 3 + 0] = a0 * sc;
      h_v[(long)u * 3 + 1] = a1 * sc;
      h_v[(long)u * 3 + 2] = a2 * sc;
    }
  } else {
    int t = (blockIdx.x - NODE_BLOCKS) * 256 + threadIdx.x;
    if (t < 4096) {                       // w1t: 64x64
      int c = t >> 6, k = t & 63;
      w1t[c * 64 + k] = f2bf(fc_w1[k * 64 + c]);
    } else if (t < 4096 + 14336) {        // w2t: 224x64
      int u = t - 4096; int c = u >> 6, k = u & 63;
      w2t[c * 64 + k] = f2bf(fc_w2[k * 224 + c]);
    } else if (t < 18432 + 9216) {        // wst: 96x96 (pre-scaled)
      int u = t - 18432; int c = u / 96, k = u - c * 96;
      wst[c * 96 + k] = f2bf(lin2_ws[k * 96 + c] * (C_INV_NN * C_INV_S96));
    } else if (t < 27648 + 4096) {        // wvt: 32x128 (pre-scaled)
      int u = t - 27648; int d = u >> 7, k = u & 127;
      wvt[d * 128 + k] = f2bf(lin2_wv[k * 32 + d] * (C_INV_NN * C_INV_S128));
    }
  }
}

// ---------------- CSR build ----------------
__global__ __launch_bounds__(256) void k_deg(const int* __restrict__ edst,
                                             int* __restrict__ deg)
{
  int e = blockIdx.x * 256 + threadIdx.x;
  if (e < N_EDGES) atomicAdd(&deg[edst[e]], 1);
}

__global__ __launch_bounds__(1024) void k_scan(const int* __restrict__ deg,
                                               int* __restrict__ start,
                                               int* __restrict__ cursor)
{
  __shared__ int psum[1024];
  int tid = threadIdx.x;
  const int PER = 40;
  int base = tid * PER;
  int s = 0;
  for (int i = 0; i < PER; ++i) {
    int idx = base + i;
    if (idx < N_NODES) s += deg[idx];
  }
  psum[tid] = s;
  __syncthreads();
  for (int off = 1; off < 1024; off <<= 1) {
    int v = psum[tid];
    int u = (tid >= off) ? psum[tid - off] : 0;
    __syncthreads();
    psum[tid] = v + u;
    __syncthreads();
  }
  int run = (tid == 0) ? 0 : psum[tid - 1];
  for (int i = 0; i < PER; ++i) {
    int idx = base + i;
    if (idx < N_NODES) {
      start[idx] = run; cursor[idx] = run;
      run += deg[idx];
    }
  }
  if (tid == 1023) start[N_NODES] = run;
}

// pos[e] = sorted slot of edge e (inverse permutation)
__global__ __launch_bounds__(256) void k_fill(const int* __restrict__ edst,
                                              int* __restrict__ cursor,
                                              int* __restrict__ pos)
{
  int e = blockIdx.x * 256 + threadIdx.x;
  if (e < N_EDGES) {
    int p = atomicAdd(&cursor[edst[e]], 1);
    pos[e] = p;
  }
}

// ---- K2: fused FC(MFMA) + messages + per-edge lin2(MFMA) -> scatter e_out ----
// Edges in ORIGINAL order (sequential reads); rows scatter-stored to sorted
// slots pos[e]. block = 4 waves x 16 edges; LDS warp-private, 0 barriers.
// Plain launch_bounds: VGPR ~84 (no spill), LDS caps at 5 blocks/CU (~62% occ).
__global__ __launch_bounds__(256) void k_edge2(
    const float* __restrict__ escal, const float* __restrict__ eattr,
    const int* __restrict__ esrc, const int* __restrict__ pos,
    const unsigned short* __restrict__ w1t, const unsigned short* __restrict__ w2t,
    const unsigned short* __restrict__ wst, const unsigned short* __restrict__ wvt,
    const float* __restrict__ h_s, const float* __restrict__ h_v,
    unsigned short* __restrict__ e_out)
{
  __shared__ unsigned short w_lds[64 * 232];    // 29.7 KB (hid + w + o reuse)
  int tid = threadIdx.x, warp = tid >> 6, lane = tid & 63;
  int lr = lane & 15, lg = lane >> 4;
  long e0 = (long)blockIdx.x * 64;
  int r0 = warp * 16;
  unsigned short* wp = w_lds + r0 * 232;        // warp-private slice

  // ---- per-lane edge ingredients (sequential edge id) ----
  long eM = e0 + r0 + lr;
  int srcM = esrc[eM];
  float4 ea4 = *reinterpret_cast<const float4*>(eattr + eM * 4);
  float ea0 = ea4.x, e1x = ea4.y, e1y = ea4.z, e1z = ea4.w;
  float esv[16];
  {
    const float* hsr = h_s + (long)srcM * 64;
    *reinterpret_cast<float4*>(&esv[0])  = *reinterpret_cast<const float4*>(hsr + lg * 8);
    *reinterpret_cast<float4*>(&esv[4])  = *reinterpret_cast<const float4*>(hsr + lg * 8 + 4);
    *reinterpret_cast<float4*>(&esv[8])  = *reinterpret_cast<const float4*>(hsr + 32 + lg * 8);
    *reinterpret_cast<float4*>(&esv[12]) = *reinterpret_cast<const float4*>(hsr + 32 + lg * 8 + 4);
  }
  float evv[24];
  {
    const float* hvr = h_v + (long)srcM * 96 + lg * 24;
    #pragma unroll
    for (int q = 0; q < 6; ++q)
      *reinterpret_cast<float4*>(&evv[4 * q]) = *reinterpret_cast<const float4*>(hvr + 4 * q);
  }

  // ---- layer1: hid = silu((escal @ W1)/8); sequential A rows ----
  f32x4 acc[4] = {};
  #pragma unroll
  for (int ks = 0; ks < 2; ++ks) {
    const float* ap = escal + eM * 64 + ks * 32 + lg * 8;
    float4 a01 = *reinterpret_cast<const float4*>(ap);
    float4 a23 = *reinterpret_cast<const float4*>(ap + 4);
    short8 af;
    af[0] = (short)f2bf(a01.x); af[1] = (short)f2bf(a01.y);
    af[2] = (short)f2bf(a01.z); af[3] = (short)f2bf(a01.w);
    af[4] = (short)f2bf(a23.x); af[5] = (short)f2bf(a23.y);
    af[6] = (short)f2bf(a23.z); af[7] = (short)f2bf(a23.w);
    #pragma unroll
    for (int nt = 0; nt < 4; ++nt) {
      short8 bf = *reinterpret_cast<const short8*>(w1t + (nt * 16 + lr) * 64 + ks * 32 + lg * 8);
      acc[nt] = __builtin_amdgcn_mfma_f32_16x16x32_bf16(af, bf, acc[nt], 0, 0, 0);
    }
  }
  #pragma unroll
  for (int nt = 0; nt < 4; ++nt)
    #pragma unroll
    for (int r = 0; r < 4; ++r) {
      float x = acc[nt][r] * C_INV8;
      float h = x / (1.f + __expf(-x));
      wp[(lg * 4 + r) * 72 + nt * 16 + lr] = f2bf(h);
    }

  // ---- layer2: w = (hid @ W2)/8 ----
  f32x4 acc2[14] = {};
  #pragma unroll
  for (int ks = 0; ks < 2; ++ks) {
    short8 af = *reinterpret_cast<const short8*>(wp + lr * 72 + ks * 32 + lg * 8);
    #pragma unroll
    for (int nt = 0; nt < 14; ++nt) {
      short8 bf = *reinterpret_cast<const short8*>(w2t + (nt * 16 + lr) * 64 + ks * 32 + lg * 8);
      acc2[nt] = __builtin_amdgcn_mfma_f32_16x16x32_bf16(af, bf, acc2[nt], 0, 0, 0);
    }
  }
  #pragma unroll
  for (int nt = 0; nt < 14; ++nt)
    #pragma unroll
    for (int r = 0; r < 4; ++r)
      wp[(lg * 4 + r) * 232 + nt * 16 + lr] = f2bf(acc2[nt][r] * C_INV8);

  const unsigned short* wrow = wp + lr * 232;
  short8 w1a = *reinterpret_cast<const short8*>(wrow + lg * 8);
  short8 w1b = *reinterpret_cast<const short8*>(wrow + 32 + lg * 8);
  short8 w2a = *reinterpret_cast<const short8*>(wrow + 64 + lg * 8);
  short8 w2b = *reinterpret_cast<const short8*>(wrow + 96 + lg * 8);
  short8 w3s = *reinterpret_cast<const short8*>(wrow + 128 + lg * 8);
  short8 w4s = *reinterpret_cast<const short8*>(wrow + 160 + lg * 8);
  short8 w5s = *reinterpret_cast<const short8*>(wrow + 192 + lg * 8);

  // ---- S-GEMM: [16 edges x 96 mid_s] @ wst -> 16x96 (scaled) ----
  f32x4 accS[6] = {};
  {
    short8 aS;
    #pragma unroll
    for (int j = 0; j < 8; ++j) aS[j] = (short)f2bf(bf2f((unsigned short)w1a[j]) * esv[j] * ea0);
    #pragma unroll
    for (int nt = 0; nt < 6; ++nt) {
      short8 b = *reinterpret_cast<const short8*>(wst + (nt * 16 + lr) * 96 + lg * 8);
      accS[nt] = __builtin_amdgcn_mfma_f32_16x16x32_bf16(aS, b, accS[nt], 0, 0, 0);
    }
    #pragma unroll
    for (int j = 0; j < 8; ++j) aS[j] = (short)f2bf(bf2f((unsigned short)w1b[j]) * esv[8 + j] * ea0);
    #pragma unroll
    for (int nt = 0; nt < 6; ++nt) {
      short8 b = *reinterpret_cast<const short8*>(wst + (nt * 16 + lr) * 96 + 32 + lg * 8);
      accS[nt] = __builtin_amdgcn_mfma_f32_16x16x32_bf16(aS, b, accS[nt], 0, 0, 0);
    }
    #pragma unroll
    for (int j = 0; j < 8; ++j) {
      float dot = evv[3 * j] * e1x + evv[3 * j + 1] * e1y + evv[3 * j + 2] * e1z;
      aS[j] = (short)f2bf(bf2f((unsigned short)w4s[j]) * dot * C_INV_S3);
    }
    #pragma unroll
    for (int nt = 0; nt < 6; ++nt) {
      short8 b = *reinterpret_cast<const short8*>(wst + (nt * 16 + lr) * 96 + 64 + lg * 8);
      accS[nt] = __builtin_amdgcn_mfma_f32_16x16x32_bf16(aS, b, accS[nt], 0, 0, 0);
    }
  }

  // ---- V-GEMMs: per comp i, [16 x 128 mid_v_i] @ wvt -> 16x32 (scaled) ----
  f32x4 accV[6] = {};
  #pragma unroll
  for (int i = 0; i < 3; ++i) {
    float e1i = (i == 0) ? e1x : (i == 1) ? e1y : e1z;
    short8 aV;
    #pragma unroll
    for (int j = 0; j < 8; ++j) aV[j] = (short)f2bf(bf2f((unsigned short)w2a[j]) * esv[j] * e1i);
    #pragma unroll
    for (int nt = 0; nt < 2; ++nt) {
      short8 b = *reinterpret_cast<const short8*>(wvt + (nt * 16 + lr) * 128 + lg * 8);
      accV[i * 2 + nt] = __builtin_amdgcn_mfma_f32_16x16x32_bf16(aV, b, accV[i * 2 + nt], 0, 0, 0);
    }
    #pragma unroll
    for (int j = 0; j < 8; ++j) aV[j] = (short)f2bf(bf2f((unsigned short)w2b[j]) * esv[8 + j] * e1i);
    #pragma unroll
    for (int nt = 0; nt < 2; ++nt) {
      short8 b = *reinterpret_cast<const short8*>(wvt + (nt * 16 + lr) * 128 + 32 + lg * 8);
      accV[i * 2 + nt] = __builtin_amdgcn_mfma_f32_16x16x32_bf16(aV, b, accV[i * 2 + nt], 0, 0, 0);
    }
    #pragma unroll
    for (int j = 0; j < 8; ++j) aV[j] = (short)f2bf(bf2f((unsigned short)w3s[j]) * evv[3 * j + i] * ea0);
    #pragma unroll
    for (int nt = 0; nt < 2; ++nt) {
      short8 b = *reinterpret_cast<const short8*>(wvt + (nt * 16 + lr) * 128 + 64 + lg * 8);
      accV[i * 2 + nt] = __builtin_amdgcn_mfma_f32_16x16x32_bf16(aV, b, accV[i * 2 + nt], 0, 0, 0);
    }
    #pragma unroll
    for (int j = 0; j < 8; ++j) {
      float ex = evv[3 * j], ey = evv[3 * j + 1], ez = evv[3 * j + 2];
      float cr = (i == 0) ? (ey * e1z - ez * e1y)
               : (i == 1) ? (ez * e1x - ex * e1z)
                          : (ex * e1y - ey * e1x);
      aV[j] = (short)f2bf(bf2f((unsigned short)w5s[j]) * cr * C_INV_S2);
    }
    #pragma unroll
    for (int nt = 0; nt < 2; ++nt) {
      short8 b = *reinterpret_cast<const short8*>(wvt + (nt * 16 + lr) * 128 + 96 + lg * 8);
      accV[i * 2 + nt] = __builtin_amdgcn_mfma_f32_16x16x32_bf16(aV, b, accV[i * 2 + nt], 0, 0, 0);
    }
  }

  // ---- stage o (192 bf16/edge) into own warp slice (stride 232) ----
  #pragma unroll
  for (int nt = 0; nt < 6; ++nt)
    #pragma unroll
    for (int r = 0; r < 4; ++r)
      wp[(lg * 4 + r) * 232 + nt * 16 + lr] = f2bf(accS[nt][r]);
  #pragma unroll
  for (int q = 0; q < 6; ++q) {
    int i = q >> 1, nt = q & 1;
    #pragma unroll
    for (int r = 0; r < 4; ++r)
      wp[(lg * 4 + r) * 232 + 96 + i * 32 + nt * 16 + lr] = f2bf(accV[q][r]);
  }

  // ---- scatter-store: row -> sorted slot pos[e] ----
  #pragma unroll
  for (int c3 = 0; c3 < 6; ++c3) {
    int chunk = c3 * 64 + lane;           // 0..383
    int row = chunk / 24, col = chunk % 24;
    int p = pos[e0 + r0 + row];           // L1-hit after first touch
    float4 v4 = *reinterpret_cast<const float4*>(wp + row * 232 + col * 8);
    *reinterpret_cast<float4*>(e_out + (long)p * 192 + col * 8) = v4;
  }
}

// ---- K3: fused streaming agg (sorted e_out) + output head; 2 nodes/block ----
__global__ __launch_bounds__(192) void k_aggfin(
    const int* __restrict__ start, const unsigned short* __restrict__ eo,
    const float* __restrict__ nf, const float* __restrict__ attr,
    const float* __restrict__ sc_ws, const float* __restrict__ sc_wv,
    float* __restrict__ out)
{
  __shared__ float sm[2][192];
  int tid = threadIdx.x;
  int ln = tid / 96, c = tid - ln * 96;
  int n = blockIdx.x * 2 + ln;

  // phase 1: stream-reduce this node's sorted rows (channels 2c, 2c+1)
  int s0 = start[n], s1 = start[n + 1];
  const unsigned int* base = reinterpret_cast<const unsigned int*>(eo);
  float a0 = 0.f, a1 = 0.f;
  long idx = (long)s0 * 96 + c;
  int k = s0;
  for (; k + 8 <= s1; k += 8) {
    unsigned int v[8];
    #pragma unroll
    for (int j = 0; j < 8; ++j) v[j] = base[idx + (long)j * 96];
    #pragma unroll
    for (int j = 0; j < 8; ++j) {
      a0 += bf2f((unsigned short)(v[j] & 0xffffu));
      a1 += bf2f((unsigned short)(v[j] >> 16));
    }
    idx += 8 * 96;
  }
  for (; k < s1; ++k) {
    unsigned int v = base[idx];
    a0 += bf2f((unsigned short)(v & 0xffffu));
    a1 += bf2f((unsigned short)(v >> 16));
    idx += 96;
  }
  sm[ln][2 * c]     = a0;
  sm[ln][2 * c + 1] = a1;
  __syncthreads();

  // phase 2: output head
  const float* s = nf + (long)n * 160;
  float a = attr[n];
  if (c < 64) {                        // scalar outputs
    float acc2 = 0.f;
    #pragma unroll 8
    for (int kk = 0; kk < 64; ++kk) acc2 = fmaf(s[kk], sc_ws[kk * 96 + c], acc2);
    float pre = (sm[ln][c] + acc2 * C_INV8) * a;
    out[(long)n * 160 + c] = pre / (1.f + __expf(-pre));
  } else {                             // vector outputs (gate recomputed)
    int d = c - 64;
    float gacc = 0.f;
    #pragma unroll 8
    for (int kk = 0; kk < 64; ++kk) gacc = fmaf(s[kk], sc_ws[kk * 96 + 64 + d], gacc);
    float gpre = (sm[ln][64 + d] + gacc * C_INV8) * a;
    float g = 1.f / (1.f + __expf(-gpre));
    const float* v = s + 64;
    float s0v = 0.f, s1v = 0.f, s2v = 0.f;
    #pragma unroll 8
    for (int cc = 0; cc < 32; ++cc) {
      float wv = sc_wv[cc * 32 + d];
      s0v = fmaf(v[3 * cc + 0], wv, s0v);
      s1v = fmaf(v[3 * cc + 1], wv, s1v);
      s2v = fmaf(v[3 * cc + 2], wv, s2v);
    }
    const float* ag = sm[ln] + 96;
    float p0 = (ag[d]      + s0v * C_INV_S32) * a;
    float p1 = (ag[32 + d] + s1v * C_INV_S32) * a;
    float p2 = (ag[64 + d] + s2v * C_INV_S32) * a;
    float* o = out + (long)n * 160 + 64 + 3 * d;
    o[0] = g * p0; o[1] = g * p1; o[2] = g * p2;
  }
}

extern "C" void kernel_launch(void* const* d_in, const int* in_sizes, int n_in,
                              void* d_out, int out_size, void* d_ws, size_t ws_size,
                              hipStream_t stream)
{
  const float* nf      = (const float*)d_in[0];
  const float* attr    = (const float*)d_in[1];
  const int*   esrc    = (const int*)d_in[2];
  const int*   edst    = (const int*)d_in[3];
  const float* eattr   = (const float*)d_in[4];
  const float* escal   = (const float*)d_in[5];
  const float* lin1_ws = (const float*)d_in[6];
  const float* lin1_wv = (const float*)d_in[7];
  const float* fc_w1   = (const float*)d_in[8];
  const float* fc_w2   = (const float*)d_in[9];
  const float* sc_ws   = (const float*)d_in[10];
  const float* sc_wv   = (const float*)d_in[11];
  const float* lin2_ws = (const float*)d_in[12];
  const float* lin2_wv = (const float*)d_in[13];
  float* out = (float*)d_out;

  char* base = (char*)d_ws;
  size_t off = 0;
  auto carve = [&](size_t bytes) { void* p = base + off; off = (off + bytes + 63) & ~(size_t)63; return p; };
  float* h_s   = (float*)carve((size_t)N_NODES * 64 * 4);
  float* h_v   = (float*)carve((size_t)N_NODES * 96 * 4);
  unsigned short* w1t = (unsigned short*)carve(4096 * 2);
  unsigned short* w2t = (unsigned short*)carve(14336 * 2);
  unsigned short* wst = (unsigned short*)carve(9216 * 2);
  unsigned short* wvt = (unsigned short*)carve(4096 * 2);
  int* deg    = (int*)carve((size_t)N_NODES * 4);
  int* startp = (int*)carve((size_t)(N_NODES + 1) * 4);
  int* cursor = (int*)carve((size_t)N_NODES * 4);
  int* pos    = (int*)carve((size_t)N_EDGES * 4);
  unsigned short* e_out = (unsigned short*)carve((size_t)N_EDGES * 192 * 2);

  k_pre<<<NODE_BLOCKS + PREP_BLOCKS, 256, 0, stream>>>(
      nf, attr, lin1_ws, lin1_wv, fc_w1, fc_w2, lin2_ws, lin2_wv,
      h_s, h_v, w1t, w2t, wst, wvt);

  hipMemsetAsync(deg, 0, (size_t)N_NODES * 4, stream);
  k_deg<<<(N_EDGES + 255) / 256, 256, 0, stream>>>(edst, deg);
  k_scan<<<1, 1024, 0, stream>>>(deg, startp, cursor);
  k_fill<<<(N_EDGES + 255) / 256, 256, 0, stream>>>(edst, cursor, pos);
  k_edge2<<<N_EDGES / 64, 256, 0, stream>>>(escal, eattr, esrc, pos,
                                            w1t, w2t, wst, wvt, h_s, h_v, e_out);
  k_aggfin<<<N_NODES / 2, 192, 0, stream>>>(startp, e_out, nf, attr,
                                            sc_ws, sc_wv, out);
}

// Round 11
// 739.237 us; speedup vs baseline: 1.0173x; 1.0173x over previous
//
#include <hip/hip_runtime.h>

constexpr int N_NODES = 40000;
constexpr int N_EDGES = 640000;

constexpr float C_INV8     = 0.125f;
constexpr float C_INV_S32  = 0.17677669529663687f;
constexpr float C_INV_S3   = 0.57735026918962576f;
constexpr float C_INV_S2   = 0.70710678118654752f;
constexpr float C_INV_S96  = 0.10206207261596575f;
constexpr float C_INV_S128 = 0.08838834764831845f;
constexpr float C_INV_NN   = 0.25f;

typedef __attribute__((ext_vector_type(8))) short short8;
typedef __attribute__((ext_vector_type(4))) float f32x4;

__device__ __forceinline__ unsigned short f2bf(float x) {
  __bf16 b = (__bf16)x;
  return __builtin_bit_cast(unsigned short, b);
}
__device__ __forceinline__ float bf2f(unsigned short h) {
  return __uint_as_float(((unsigned int)h) << 16);
}
__device__ __forceinline__ unsigned int pk2(float a, float b) {
  return (unsigned int)f2bf(a) | ((unsigned int)f2bf(b) << 16);
}
__device__ __forceinline__ float unlo(unsigned int v) { return __uint_as_float(v << 16); }
__device__ __forceinline__ float unhi(unsigned int v) { return __uint_as_float(v & 0xffff0000u); }
#define PKGET(buf, j) (((j) & 1) ? unhi(buf[(j) >> 1]) : unlo(buf[(j) >> 1]))

__device__ __forceinline__ short8 mk8(const unsigned int* p) {
  union { unsigned int u[4]; short8 s; } cv;
  cv.u[0] = p[0]; cv.u[1] = p[1]; cv.u[2] = p[2]; cv.u[3] = p[3];
  return cv.s;
}

// ---- K1: node linears + weight prep + degree count (block-range split) ----
constexpr int NODE_BLOCKS = (N_NODES * 96 + 255) / 256;   // 15000
constexpr int PREP_BLOCKS = 124;
constexpr int DEG_BLOCKS  = N_EDGES / 256;                // 2500

__global__ __launch_bounds__(256) void k_pre(
    const float* __restrict__ nf, const float* __restrict__ attr,
    const float* __restrict__ ws_, const float* __restrict__ wv_,
    const float* __restrict__ fc_w1, const float* __restrict__ fc_w2,
    const float* __restrict__ lin2_ws, const float* __restrict__ lin2_wv,
    const int* __restrict__ edst, int* __restrict__ deg,
    float* __restrict__ h_s, float* __restrict__ h_v,
    unsigned short* __restrict__ w1t, unsigned short* __restrict__ w2t,
    unsigned short* __restrict__ wst, unsigned short* __restrict__ wvt)
{
  if (blockIdx.x < NODE_BLOCKS) {
    int t = blockIdx.x * 256 + threadIdx.x;
    if (t < N_NODES * 64) {
      int n = t >> 6, c = t & 63;
      const float* s = nf + (long)n * 160;
      float acc = 0.f;
      #pragma unroll 8
      for (int k = 0; k < 64; ++k) acc = fmaf(s[k], ws_[k * 64 + c], acc);
      h_s[t] = acc * attr[n] * C_INV8;
    } else {
      int u = t - N_NODES * 64;
      if (u >= N_NODES * 32) return;
      int n = u >> 5, d = u & 31;
      const float* v = nf + (long)n * 160 + 64;
      float a0 = 0.f, a1 = 0.f, a2 = 0.f;
      #pragma unroll 8
      for (int c = 0; c < 32; ++c) {
        float wv = wv_[c * 32 + d];
        a0 = fmaf(v[3 * c + 0], wv, a0);
        a1 = fmaf(v[3 * c + 1], wv, a1);
        a2 = fmaf(v[3 * c + 2], wv, a2);
      }
      float sc = attr[n] * C_INV_S32;
      h_v[(long)u * 3 + 0] = a0 * sc;
      h_v[(long)u * 3 + 1] = a1 * sc;
      h_v[(long)u * 3 + 2] = a2 * sc;
    }
  } else if (blockIdx.x < NODE_BLOCKS + PREP_BLOCKS) {
    int t = (blockIdx.x - NODE_BLOCKS) * 256 + threadIdx.x;
    if (t < 4096) {
      int c = t >> 6, k = t & 63;
      w1t[c * 64 + k] = f2bf(fc_w1[k * 64 + c]);
    } else if (t < 4096 + 14336) {
      int u = t - 4096; int c = u >> 6, k = u & 63;
      w2t[c * 64 + k] = f2bf(fc_w2[k * 224 + c]);
    } else if (t < 18432 + 9216) {
      int u = t - 18432; int c = u / 96, k = u - c * 96;
      wst[c * 96 + k] = f2bf(lin2_ws[k * 96 + c] * (C_INV_NN * C_INV_S96));
    } else if (t < 27648 + 4096) {
      int u = t - 27648; int d = u >> 7, k = u & 127;
      wvt[d * 128 + k] = f2bf(lin2_wv[k * 32 + d] * (C_INV_NN * C_INV_S128));
    }
  } else {
    int e = (blockIdx.x - NODE_BLOCKS - PREP_BLOCKS) * 256 + threadIdx.x;
    if (e < N_EDGES) atomicAdd(&deg[edst[e]], 1);
  }
}

__global__ __launch_bounds__(1024) void k_scan(const int* __restrict__ deg,
                                               int* __restrict__ start,
                                               int* __restrict__ cursor)
{
  __shared__ int psum[1024];
  int tid = threadIdx.x;
  const int PER = 40;
  int base = tid * PER;
  int s = 0;
  for (int i = 0; i < PER; ++i) {
    int idx = base + i;
    if (idx < N_NODES) s += deg[idx];
  }
  psum[tid] = s;
  __syncthreads();
  for (int off = 1; off < 1024; off <<= 1) {
    int v = psum[tid];
    int u = (tid >= off) ? psum[tid - off] : 0;
    __syncthreads();
    psum[tid] = v + u;
    __syncthreads();
  }
  int run = (tid == 0) ? 0 : psum[tid - 1];
  for (int i = 0; i < PER; ++i) {
    int idx = base + i;
    if (idx < N_NODES) {
      start[idx] = run; cursor[idx] = run;
      run += deg[idx];
    }
  }
  if (tid == 1023) start[N_NODES] = run;
}

// ---- K2: 64 edges/wave, 4-group software pipeline; in-kernel slot atomics ----
#define PRE_G(g, scl_, esv_, evv_, ea_)                                        \
{                                                                              \
  long eM_ = eW + (g) * 16 + lr;                                               \
  int s_ = srcs[g];                                                            \
  ea_ = *reinterpret_cast<const float4*>(eattr + eM_ * 4);                     \
  const float* ap_ = escal + eM_ * 64 + lg * 8;                                \
  float4 x0 = *reinterpret_cast<const float4*>(ap_);                           \
  float4 x1 = *reinterpret_cast<const float4*>(ap_ + 4);                       \
  float4 x2 = *reinterpret_cast<const float4*>(ap_ + 32);                      \
  float4 x3 = *reinterpret_cast<const float4*>(ap_ + 36);                      \
  const float* hs_ = h_s + (long)s_ * 64 + lg * 8;                             \
  float4 h0 = *reinterpret_cast<const float4*>(hs_);                           \
  float4 h1 = *reinterpret_cast<const float4*>(hs_ + 4);                       \
  float4 h2 = *reinterpret_cast<const float4*>(hs_ + 32);                      \
  float4 h3 = *reinterpret_cast<const float4*>(hs_ + 36);                      \
  const float* hv_ = h_v + (long)s_ * 96 + lg * 24;                            \
  float4 v0 = *reinterpret_cast<const float4*>(hv_);                           \
  float4 v1 = *reinterpret_cast<const float4*>(hv_ + 4);                       \
  float4 v2 = *reinterpret_cast<const float4*>(hv_ + 8);                       \
  float4 v3 = *reinterpret_cast<const float4*>(hv_ + 12);                      \
  float4 v4 = *reinterpret_cast<const float4*>(hv_ + 16);                      \
  float4 v5 = *reinterpret_cast<const float4*>(hv_ + 20);                      \
  scl_[0] = pk2(x0.x, x0.y); scl_[1] = pk2(x0.z, x0.w);                        \
  scl_[2] = pk2(x1.x, x1.y); scl_[3] = pk2(x1.z, x1.w);                        \
  scl_[4] = pk2(x2.x, x2.y); scl_[5] = pk2(x2.z, x2.w);                        \
  scl_[6] = pk2(x3.x, x3.y); scl_[7] = pk2(x3.z, x3.w);                        \
  esv_[0] = pk2(h0.x, h0.y); esv_[1] = pk2(h0.z, h0.w);                        \
  esv_[2] = pk2(h1.x, h1.y); esv_[3] = pk2(h1.z, h1.w);                        \
  esv_[4] = pk2(h2.x, h2.y); esv_[5] = pk2(h2.z, h2.w);                        \
  esv_[6] = pk2(h3.x, h3.y); esv_[7] = pk2(h3.z, h3.w);                        \
  evv_[0] = pk2(v0.x, v0.y); evv_[1] = pk2(v0.z, v0.w);                        \
  evv_[2] = pk2(v1.x, v1.y); evv_[3] = pk2(v1.z, v1.w);                        \
  evv_[4] = pk2(v2.x, v2.y); evv_[5] = pk2(v2.z, v2.w);                        \
  evv_[6] = pk2(v3.x, v3.y); evv_[7] = pk2(v3.z, v3.w);                        \
  evv_[8] = pk2(v4.x, v4.y); evv_[9] = pk2(v4.z, v4.w);                        \
  evv_[10] = pk2(v5.x, v5.y); evv_[11] = pk2(v5.z, v5.w);                      \
}

#define COMP_G(g, scl_, esv_, evv_, ea_)                                       \
{                                                                              \
  float ea0 = ea_.x, e1x = ea_.y, e1y = ea_.z, e1z = ea_.w;                    \
  {                                                                            \
    f32x4 acc[4] = {};                                                         \
    short8 af0 = mk8(scl_);                                                    \
    short8 af1 = mk8(scl_ + 4);                                                \
    _Pragma("unroll")                                                          \
    for (int nt = 0; nt < 4; ++nt) {                                           \
      short8 b0 = *reinterpret_cast<const short8*>(w1t + (nt * 16 + lr) * 64 + lg * 8);      \
      short8 b1 = *reinterpret_cast<const short8*>(w1t + (nt * 16 + lr) * 64 + 32 + lg * 8); \
      acc[nt] = __builtin_amdgcn_mfma_f32_16x16x32_bf16(af0, b0, acc[nt], 0, 0, 0);          \
      acc[nt] = __builtin_amdgcn_mfma_f32_16x16x32_bf16(af1, b1, acc[nt], 0, 0, 0);          \
    }                                                                          \
    _Pragma("unroll")                                                          \
    for (int nt = 0; nt < 4; ++nt)                                             \
      _Pragma("unroll")                                                        \
      for (int r = 0; r < 4; ++r) {                                            \
        float x = acc[nt][r] * C_INV8;                                         \
        float h = x / (1.f + __expf(-x));                                      \
        wp[(lg * 4 + r) * 72 + nt * 16 + lr] = f2bf(h);                        \
      }                                                                        \
  }                                                                            \
  {                                                                            \
    short8 a20 = *reinterpret_cast<const short8*>(wp + lr * 72 + lg * 8);      \
    short8 a21 = *reinterpret_cast<const short8*>(wp + lr * 72 + 32 + lg * 8); \
    _Pragma("unroll")                                                          \
    for (int nt = 0; nt < 14; ++nt) {                                          \
      short8 b0 = *reinterpret_cast<const short8*>(w2t + (nt * 16 + lr) * 64 + lg * 8);      \
      short8 b1 = *reinterpret_cast<const short8*>(w2t + (nt * 16 + lr) * 64 + 32 + lg * 8); \
      f32x4 a2 = {};                                                           \
      a2 = __builtin_amdgcn_mfma_f32_16x16x32_bf16(a20, b0, a2, 0, 0, 0);      \
      a2 = __builtin_amdgcn_mfma_f32_16x16x32_bf16(a21, b1, a2, 0, 0, 0);      \
      _Pragma("unroll")                                                        \
      for (int r = 0; r < 4; ++r)                                              \
        wp[(lg * 4 + r) * 232 + nt * 16 + lr] = f2bf(a2[r] * C_INV8);          \
    }                                                                          \
  }                                                                            \
  const unsigned short* wrow = wp + lr * 232;                                  \
  short8 w1a = *reinterpret_cast<const short8*>(wrow + lg * 8);                \
  short8 w1b = *reinterpret_cast<const short8*>(wrow + 32 + lg * 8);           \
  short8 w2a = *reinterpret_cast<const short8*>(wrow + 64 + lg * 8);           \
  short8 w2b = *reinterpret_cast<const short8*>(wrow + 96 + lg * 8);           \
  short8 w3s = *reinterpret_cast<const short8*>(wrow + 128 + lg * 8);          \
  short8 w4s = *reinterpret_cast<const short8*>(wrow + 160 + lg * 8);          \
  short8 w5s = *reinterpret_cast<const short8*>(wrow + 192 + lg * 8);          \
  f32x4 accS[6] = {};                                                          \
  {                                                                            \
    short8 aS;                                                                 \
    _Pragma("unroll")                                                          \
    for (int j = 0; j < 8; ++j)                                                \
      aS[j] = (short)f2bf(bf2f((unsigned short)w1a[j]) * PKGET(esv_, j) * ea0);\
    _Pragma("unroll")                                                          \
    for (int nt = 0; nt < 6; ++nt) {                                           \
      short8 b = *reinterpret_cast<const short8*>(wst + (nt * 16 + lr) * 96 + lg * 8);       \
      accS[nt] = __builtin_amdgcn_mfma_f32_16x16x32_bf16(aS, b, accS[nt], 0, 0, 0);          \
    }                                                                          \
    _Pragma("unroll")                                                          \
    for (int j = 0; j < 8; ++j)                                                \
      aS[j] = (short)f2bf(bf2f((unsigned short)w1b[j]) * PKGET(esv_, 8 + j) * ea0);          \
    _Pragma("unroll")                                                          \
    for (int nt = 0; nt < 6; ++nt) {                                           \
      short8 b = *reinterpret_cast<const short8*>(wst + (nt * 16 + lr) * 96 + 32 + lg * 8);  \
      accS[nt] = __builtin_amdgcn_mfma_f32_16x16x32_bf16(aS, b, accS[nt], 0, 0, 0);          \
    }                                                                          \
    _Pragma("unroll")                                                          \
    for (int j = 0; j < 8; ++j) {                                              \
      float dot = PKGET(evv_, 3 * j) * e1x + PKGET(evv_, 3 * j + 1) * e1y      \
                + PKGET(evv_, 3 * j + 2) * e1z;                                \
      aS[j] = (short)f2bf(bf2f((unsigned short)w4s[j]) * dot * C_INV_S3);      \
    }                                                                          \
    _Pragma("unroll")                                                          \
    for (int nt = 0; nt < 6; ++nt) {                                           \
      short8 b = *reinterpret_cast<const short8*>(wst + (nt * 16 + lr) * 96 + 64 + lg * 8);  \
      accS[nt] = __builtin_amdgcn_mfma_f32_16x16x32_bf16(aS, b, accS[nt], 0, 0, 0);          \
    }                                                                          \
  }                                                                            \
  f32x4 accV[6] = {};                                                          \
  _Pragma("unroll")                                                            \
  for (int i = 0; i < 3; ++i) {                                                \
    float e1i = (i == 0) ? e1x : (i == 1) ? e1y : e1z;                         \
    short8 aV;                                                                 \
    _Pragma("unroll")                                                          \
    for (int j = 0; j < 8; ++j)                                                \
      aV[j] = (short)f2bf(bf2f((unsigned short)w2a[j]) * PKGET(esv_, j) * e1i);\
    _Pragma("unroll")                                                          \
    for (int nt = 0; nt < 2; ++nt) {                                           \
      short8 b = *reinterpret_cast<const short8*>(wvt + (nt * 16 + lr) * 128 + lg * 8);      \
      accV[i * 2 + nt] = __builtin_amdgcn_mfma_f32_16x16x32_bf16(aV, b, accV[i * 2 + nt], 0, 0, 0); \
    }                                                                          \
    _Pragma("unroll")                                                          \
    for (int j = 0; j < 8; ++j)                                                \
      aV[j] = (short)f2bf(bf2f((unsigned short)w2b[j]) * PKGET(esv_, 8 + j) * e1i);          \
    _Pragma("unroll")                                                          \
    for (int nt = 0; nt < 2; ++nt) {                                           \
      short8 b = *reinterpret_cast<const short8*>(wvt + (nt * 16 + lr) * 128 + 32 + lg * 8); \
      accV[i * 2 + nt] = __builtin_amdgcn_mfma_f32_16x16x32_bf16(aV, b, accV[i * 2 + nt], 0, 0, 0); \
    }                                                                          \
    _Pragma("unroll")                                                          \
    for (int j = 0; j < 8; ++j)                                                \
      aV[j] = (short)f2bf(bf2f((unsigned short)w3s[j]) * PKGET(evv_, 3 * j + i) * ea0);      \
    _Pragma("unroll")                                                          \
    for (int nt = 0; nt < 2; ++nt) {                                           \
      short8 b = *reinterpret_cast<const short8*>(wvt + (nt * 16 + lr) * 128 + 64 + lg * 8); \
      accV[i * 2 + nt] = __builtin_amdgcn_mfma_f32_16x16x32_bf16(aV, b, accV[i * 2 + nt], 0, 0, 0); \
    }                                                                          \
    _Pragma("unroll")                                                          \
    for (int j = 0; j < 8; ++j) {                                              \
      float ex = PKGET(evv_, 3 * j), ey = PKGET(evv_, 3 * j + 1), ez = PKGET(evv_, 3 * j + 2); \
      float cr = (i == 0) ? (ey * e1z - ez * e1y)                              \
               : (i == 1) ? (ez * e1x - ex * e1z)                              \
                          : (ex * e1y - ey * e1x);                             \
      aV[j] = (short)f2bf(bf2f((unsigned short)w5s[j]) * cr * C_INV_S2);       \
    }                                                                          \
    _Pragma("unroll")                                                          \
    for (int nt = 0; nt < 2; ++nt) {                                           \
      short8 b = *reinterpret_cast<const short8*>(wvt + (nt * 16 + lr) * 128 + 96 + lg * 8); \
      accV[i * 2 + nt] = __builtin_amdgcn_mfma_f32_16x16x32_bf16(aV, b, accV[i * 2 + nt], 0, 0, 0); \
    }                                                                          \
  }                                                                            \
  _Pragma("unroll")                                                            \
  for (int nt = 0; nt < 6; ++nt)                                               \
    _Pragma("unroll")                                                          \
    for (int r = 0; r < 4; ++r)                                                \
      wp[(lg * 4 + r) * 232 + nt * 16 + lr] = f2bf(accS[nt][r]);               \
  _Pragma("unroll")                                                            \
  for (int q = 0; q < 6; ++q) {                                                \
    int i = q >> 1, nt = q & 1;                                                \
    _Pragma("unroll")                                                          \
    for (int r = 0; r < 4; ++r)                                                \
      wp[(lg * 4 + r) * 232 + 96 + i * 32 + nt * 16 + lr] = f2bf(accV[q][r]);  \
  }                                                                            \
  int p_mine = 0;                                                              \
  if (lane < 16) p_mine = atomicAdd(&cursor[myDst[g]], 1);                     \
  _Pragma("unroll")                                                            \
  for (int c3 = 0; c3 < 6; ++c3) {                                             \
    int chunk = c3 * 64 + lane;                                                \
    int row = chunk / 24, col = chunk % 24;                                    \
    int p = __shfl(p_mine, row);                                               \
    float4 vv = *reinterpret_cast<const float4*>(wp + row * 232 + col * 8);    \
    *reinterpret_cast<float4*>(e_out + (long)p * 192 + col * 8) = vv;          \
  }                                                                            \
}

__global__ __launch_bounds__(256) void k_edge2(
    const float* __restrict__ escal, const float* __restrict__ eattr,
    const int* __restrict__ esrc, const int* __restrict__ edst,
    int* __restrict__ cursor,
    const unsigned short* __restrict__ w1t, const unsigned short* __restrict__ w2t,
    const unsigned short* __restrict__ wst, const unsigned short* __restrict__ wvt,
    const float* __restrict__ h_s, const float* __restrict__ h_v,
    unsigned short* __restrict__ e_out)
{
  __shared__ unsigned short w_lds[64 * 232];    // 4 warp-private 16-row slices
  int tid = threadIdx.x, warp = tid >> 6, lane = tid & 63;
  int lr = lane & 15, lg = lane >> 4;
  long eW = (long)blockIdx.x * 256 + warp * 64;
  unsigned short* wp = w_lds + (warp * 16) * 232;

  int myDst[4];
  if (lane < 16) {
    #pragma unroll
    for (int g = 0; g < 4; ++g) myDst[g] = edst[eW + g * 16 + lane];
  }
  int srcs[4];
  #pragma unroll
  for (int g = 0; g < 4; ++g) srcs[g] = esrc[eW + g * 16 + lr];

  unsigned int sclA[8], esvA[8], evvA[12]; float4 eaA;
  unsigned int sclB[8], esvB[8], evvB[12]; float4 eaB;

  PRE_G(0, sclA, esvA, evvA, eaA)
  PRE_G(1, sclB, esvB, evvB, eaB)
  COMP_G(0, sclA, esvA, evvA, eaA)
  PRE_G(2, sclA, esvA, evvA, eaA)
  COMP_G(1, sclB, esvB, evvB, eaB)
  PRE_G(3, sclB, esvB, evvB, eaB)
  COMP_G(2, sclA, esvA, evvA, eaA)
  COMP_G(3, sclB, esvB, evvB, eaB)
}

// ---- K3: fused streaming agg (sorted e_out) + output head; 2 nodes/block ----
__global__ __launch_bounds__(192) void k_aggfin(
    const int* __restrict__ start, const unsigned short* __restrict__ eo,
    const float* __restrict__ nf, const float* __restrict__ attr,
    const float* __restrict__ sc_ws, const float* __restrict__ sc_wv,
    float* __restrict__ out)
{
  __shared__ float sm[2][192];
  int tid = threadIdx.x;
  int ln = tid / 96, c = tid - ln * 96;
  int n = blockIdx.x * 2 + ln;

  int s0 = start[n], s1 = start[n + 1];
  const unsigned int* base = reinterpret_cast<const unsigned int*>(eo);
  float a0 = 0.f, a1 = 0.f;
  long idx = (long)s0 * 96 + c;
  int k = s0;
  for (; k + 8 <= s1; k += 8) {
    unsigned int v[8];
    #pragma unroll
    for (int j = 0; j < 8; ++j) v[j] = base[idx + (long)j * 96];
    #pragma unroll
    for (int j = 0; j < 8; ++j) {
      a0 += bf2f((unsigned short)(v[j] & 0xffffu));
      a1 += bf2f((unsigned short)(v[j] >> 16));
    }
    idx += 8 * 96;
  }
  for (; k < s1; ++k) {
    unsigned int v = base[idx];
    a0 += bf2f((unsigned short)(v & 0xffffu));
    a1 += bf2f((unsigned short)(v >> 16));
    idx += 96;
  }
  sm[ln][2 * c]     = a0;
  sm[ln][2 * c + 1] = a1;
  __syncthreads();

  const float* s = nf + (long)n * 160;
  float a = attr[n];
  if (c < 64) {
    float acc2 = 0.f;
    #pragma unroll 8
    for (int kk = 0; kk < 64; ++kk) acc2 = fmaf(s[kk], sc_ws[kk * 96 + c], acc2);
    float pre = (sm[ln][c] + acc2 * C_INV8) * a;
    out[(long)n * 160 + c] = pre / (1.f + __expf(-pre));
  } else {
    int d = c - 64;
    float gacc = 0.f;
    #pragma unroll 8
    for (int kk = 0; kk < 64; ++kk) gacc = fmaf(s[kk], sc_ws[kk * 96 + 64 + d], gacc);
    float gpre = (sm[ln][64 + d] + gacc * C_INV8) * a;
    float g = 1.f / (1.f + __expf(-gpre));
    const float* v = s + 64;
    float s0v = 0.f, s1v = 0.f, s2v = 0.f;
    #pragma unroll 8
    for (int cc = 0; cc < 32; ++cc) {
      float wv = sc_wv[cc * 32 + d];
      s0v = fmaf(v[3 * cc + 0], wv, s0v);
      s1v = fmaf(v[3 * cc + 1], wv, s1v);
      s2v = fmaf(v[3 * cc + 2], wv, s2v);
    }
    const float* ag = sm[ln] + 96;
    float p0 = (ag[d]      + s0v * C_INV_S32) * a;
    float p1 = (ag[32 + d] + s1v * C_INV_S32) * a;
    float p2 = (ag[64 + d] + s2v * C_INV_S32) * a;
    float* o = out + (long)n * 160 + 64 + 3 * d;
    o[0] = g * p0; o[1] = g * p1; o[2] = g * p2;
  }
}

extern "C" void kernel_launch(void* const* d_in, const int* in_sizes, int n_in,
                              void* d_out, int out_size, void* d_ws, size_t ws_size,
                              hipStream_t stream)
{
  const float* nf      = (const float*)d_in[0];
  const float* attr    = (const float*)d_in[1];
  const int*   esrc    = (const int*)d_in[2];
  const int*   edst    = (const int*)d_in[3];
  const float* eattr   = (const float*)d_in[4];
  const float* escal   = (const float*)d_in[5];
  const float* lin1_ws = (const float*)d_in[6];
  const float* lin1_wv = (const float*)d_in[7];
  const float* fc_w1   = (const float*)d_in[8];
  const float* fc_w2   = (const float*)d_in[9];
  const float* sc_ws   = (const float*)d_in[10];
  const float* sc_wv   = (const float*)d_in[11];
  const float* lin2_ws = (const float*)d_in[12];
  const float* lin2_wv = (const float*)d_in[13];
  float* out = (float*)d_out;

  char* base = (char*)d_ws;
  size_t off = 0;
  auto carve = [&](size_t bytes) { void* p = base + off; off = (off + bytes + 63) & ~(size_t)63; return p; };
  float* h_s   = (float*)carve((size_t)N_NODES * 64 * 4);
  float* h_v   = (float*)carve((size_t)N_NODES * 96 * 4);
  unsigned short* w1t = (unsigned short*)carve(4096 * 2);
  unsigned short* w2t = (unsigned short*)carve(14336 * 2);
  unsigned short* wst = (unsigned short*)carve(9216 * 2);
  unsigned short* wvt = (unsigned short*)carve(4096 * 2);
  int* deg    = (int*)carve((size_t)N_NODES * 4);
  int* startp = (int*)carve((size_t)(N_NODES + 1) * 4);
  int* cursor = (int*)carve((size_t)N_NODES * 4);
  unsigned short* e_out = (unsigned short*)carve((size_t)N_EDGES * 192 * 2);

  hipMemsetAsync(deg, 0, (size_t)N_NODES * 4, stream);
  k_pre<<<NODE_BLOCKS + PREP_BLOCKS + DEG_BLOCKS, 256, 0, stream>>>(
      nf, attr, lin1_ws, lin1_wv, fc_w1, fc_w2, lin2_ws, lin2_wv,
      edst, deg, h_s, h_v, w1t, w2t, wst, wvt);
  k_scan<<<1, 1024, 0, stream>>>(deg, startp, cursor);
  k_edge2<<<N_EDGES / 256, 256, 0, stream>>>(escal, eattr, esrc, edst, cursor,
                                             w1t, w2t, wst, wvt, h_s, h_v, e_out);
  k_aggfin<<<N_NODES / 2, 192, 0, stream>>>(startp, e_out, nf, attr,
                                            sc_ws, sc_wv, out);
}